// Round 6
// baseline (112.142 us; speedup 1.0000x reference)
//
#include <hip/hip_runtime.h>
#include <hip/hip_bf16.h>
#include <math.h>

#define NN 50000
#define NE 800000
#define HD 128
#define NB ((NN + 127) >> 7)                        // 391 buckets (128 nodes each)
#define GCAP 3072                                   // max edges per bucket (mean ~2048)
#define PART_EPB 4096
#define PART_NBLK ((NE + PART_EPB - 1) / PART_EPB)  // 196
#define AGB ((NN + 31) / 32)                        // 1563 fused agg+gemm blocks

typedef unsigned int u32;
typedef unsigned short u16;
typedef __attribute__((ext_vector_type(8))) __bf16 bf16x8;
typedef __attribute__((ext_vector_type(4))) float f32x4;

__device__ __forceinline__ u16 f2bf(float f) {
    u32 u = __float_as_uint(f);
    u32 r = u + 0x7FFFu + ((u >> 16) & 1u);   // round-to-nearest-even
    return (u16)(r >> 16);
}
__device__ __forceinline__ void unpack8(uint4 p, float* f) {
    f[0] = __uint_as_float(p.x << 16); f[1] = __uint_as_float(p.x & 0xFFFF0000u);
    f[2] = __uint_as_float(p.y << 16); f[3] = __uint_as_float(p.y & 0xFFFF0000u);
    f[4] = __uint_as_float(p.z << 16); f[5] = __uint_as_float(p.z & 0xFFFF0000u);
    f[6] = __uint_as_float(p.w << 16); f[7] = __uint_as_float(p.w & 0xFFFF0000u);
}

// ---- prep: zero bucket counters, W -> MFMA fragment layout ----
// Tile t = c0*4+k0. Lane ln, elem j holds W[k0*32+(ln>>4)*8+j][(ln&15)*8 + c0],
// so a lane's 8 c0-outputs are 8 consecutive columns (coalesced C stores).
__global__ void prep_kernel(const float* __restrict__ W, u16* __restrict__ wf,
                            u32* __restrict__ bcnt) {
    int idx = blockIdx.x * blockDim.x + threadIdx.x;   // 64 blocks x 256
    if (idx < NB) bcnt[idx] = 0u;
    if (idx < HD * HD) {
        int t  = idx >> 9;           // 0..31
        int c0 = t >> 2, k0 = t & 3;
        int ln = (idx >> 3) & 63;
        int j  = idx & 7;
        int k  = k0 * 32 + (ln >> 4) * 8 + j;
        int c  = (ln & 15) * 8 + c0;
        wf[idx] = f2bf(W[k * HD + c]);
    }
}

// ---- pass 1: radix-partition edges into NB buckets ----
__global__ __launch_bounds__(256) void part_kernel(const int* __restrict__ src,
                                                   const int* __restrict__ dst,
                                                   u32* __restrict__ bcnt,
                                                   u32* __restrict__ ebuf) {
    __shared__ u32 lh[NB];
    __shared__ u32 lbase[NB];
    const int tid = threadIdx.x;
    const int e0 = blockIdx.x * PART_EPB;
    for (int i = tid; i < NB; i += 256) lh[i] = 0u;
    __syncthreads();
    #pragma unroll
    for (int j = 0; j < PART_EPB / 256; ++j) {
        int e = e0 + j * 256 + tid;
        if (e < NE) atomicAdd(&lh[dst[e] >> 7], 1u);
    }
    __syncthreads();
    for (int i = tid; i < NB; i += 256) {
        u32 c = lh[i];
        lbase[i] = c ? atomicAdd(&bcnt[i], c) : 0u;
        lh[i] = 0u;                       // reuse as local cursor
    }
    __syncthreads();
    #pragma unroll
    for (int j = 0; j < PART_EPB / 256; ++j) {
        int e = e0 + j * 256 + tid;
        if (e < NE) {
            int d = dst[e], s = src[e];
            int bkt = d >> 7;
            u32 r = atomicAdd(&lh[bkt], 1u);
            u32 pos = lbase[bkt] + r;
            if (pos < GCAP)
                ebuf[(size_t)bkt * GCAP + pos] = (u32)s | ((u32)(d & 127) << 16);
        }
    }
}

// ---- exclusive scan of NB bucket counts (single block) ----
__global__ __launch_bounds__(512) void bscan_kernel(const u32* __restrict__ bcnt,
                                                    u32* __restrict__ bstart) {
    __shared__ u32 wsum[8];
    const int tid = threadIdx.x;
    const int lane = tid & 63, wv = tid >> 6;
    u32 v = (tid < NB) ? bcnt[tid] : 0u;
    u32 inc = v;
    #pragma unroll
    for (int off = 1; off < 64; off <<= 1) {
        u32 y = __shfl_up(inc, off, 64);
        if (lane >= off) inc += y;
    }
    if (lane == 63) wsum[wv] = inc;
    __syncthreads();
    u32 woff = 0;
    #pragma unroll
    for (int j = 0; j < 8; ++j) if (j < wv) woff += wsum[j];
    if (tid < NB) bstart[tid] = woff + inc - v;
}

// ---- pass 2: per-bucket CSR build entirely in LDS ----
__global__ __launch_bounds__(256) void bucket_kernel(const u32* __restrict__ ebuf,
                                                     const u32* __restrict__ bcnt,
                                                     const u32* __restrict__ bstart,
                                                     u32* __restrict__ rowptr,
                                                     float* __restrict__ dinv,
                                                     u16* __restrict__ srclist) {
    __shared__ u32 cnt[128], loc[128], cur[128];
    __shared__ u16 stage[GCAP];
    const int tid = threadIdx.x;
    const int b = blockIdx.x;
    const int n0 = b << 7;
    u32 m = bcnt[b]; if (m > GCAP) m = GCAP;
    const u32 base = bstart[b];
    if (tid < 128) { cnt[tid] = 0u; cur[tid] = 0u; }
    __syncthreads();
    for (u32 i = tid; i < m; i += 256)
        atomicAdd(&cnt[ebuf[(size_t)b * GCAP + i] >> 16], 1u);
    __syncthreads();
    if (tid < 64) {
        u32 c0 = cnt[2 * tid], c1 = cnt[2 * tid + 1];
        u32 s = c0 + c1, inc = s;
        #pragma unroll
        for (int off = 1; off < 64; off <<= 1) {
            u32 y = __shfl_up(inc, off, 64);
            if (tid >= off) inc += y;
        }
        loc[2 * tid]     = inc - s;
        loc[2 * tid + 1] = inc - s + c0;
    }
    __syncthreads();
    if (tid < 128) {
        int node = n0 + tid;
        if (node < NN) {
            rowptr[node] = base + loc[tid];
            dinv[node] = rsqrtf((float)(cnt[tid] + 1u));
        }
    }
    for (u32 i = tid; i < m; i += 256) {
        u32 v = ebuf[(size_t)b * GCAP + i];
        u32 nl = v >> 16;
        u32 r = atomicAdd(&cur[nl], 1u);
        stage[loc[nl] + r] = (u16)(v & 0xFFFFu);
    }
    __syncthreads();
    for (u32 i = tid; i < m; i += 256) srclist[base + i] = stage[i];
    if (b == 0 && tid == 0) rowptr[NN] = NE;
}

// ---- xscale: xs[u] = bf16(dinv[u] * x[u]) ----
__global__ __launch_bounds__(256) void xscale_kernel(const float* __restrict__ x,
                                                     const float* __restrict__ dinv,
                                                     u16* __restrict__ xs) {
    int idx = blockIdx.x * blockDim.x + threadIdx.x;   // NN*HD/4 threads
    float dv = dinv[idx >> 5];
    const float4 v = reinterpret_cast<const float4*>(x)[idx];
    u32 lo = (u32)f2bf(dv * v.x) | ((u32)f2bf(dv * v.y) << 16);
    u32 hi = (u32)f2bf(dv * v.z) | ((u32)f2bf(dv * v.w) << 16);
    reinterpret_cast<uint2*>(xs)[idx] = make_uint2(lo, hi);
}

// ---- fused aggregation + MFMA GEMM ----
// 512 thr = 8 waves = 32 nodes/block. Phase 1: wave aggregates 4 nodes
// (4x16 edge-slot/feature split), rows -> XOR-swizzled LDS bf16 tile.
// Phase 2: 32x128 GEMM, wave = (row-tile, col-quarter), fused bias+BN partials.
__global__ __launch_bounds__(512, 8) void aggemm_kernel(
        const u16* __restrict__ xs, const u32* __restrict__ rowptr,
        const u16* __restrict__ srclist, const float* __restrict__ dinv,
        const u16* __restrict__ wf, const float* __restrict__ bias,
        u16* __restrict__ agg, float* __restrict__ colpart) {
    __shared__ u16 As[32 * 128];          // 8KB, chunk-swizzled: chunk ^= (row&7)
    __shared__ float cs_l[128], cq_l[128];
    const int tid = threadIdx.x;
    const int lane = tid & 63, wave = tid >> 6;
    const int eq = lane >> 4, l15 = lane & 15;
    const int base = blockIdx.x * 32;
    if (tid < 128) { cs_l[tid] = 0.f; cq_l[tid] = 0.f; }

    // ---- phase 1: aggregate 4 nodes per wave ----
    for (int t = 0; t < 4; ++t) {
        const int r = wave * 4 + t;       // LDS row 0..31
        const int v = base + r;
        float acc[8] = {};
        float dv = 0.f;
        if (v < NN) {
            dv = dinv[v];
            {   // self loop: xs[v] already carries dv
                uint4 sv = reinterpret_cast<const uint4*>(xs + (size_t)v * HD)[l15];
                float f[8]; unpack8(sv, f);
                if (eq == 0) {
                    #pragma unroll
                    for (int j = 0; j < 8; ++j) acc[j] = f[j];
                }
            }
            const u32 rs = rowptr[v], re = rowptr[v + 1];
            for (u32 i = rs + eq; i < re; i += 4) {
                u32 u = (u32)srclist[i];
                uint4 mu = reinterpret_cast<const uint4*>(xs + (size_t)u * HD)[l15];
                float f[8]; unpack8(mu, f);
                #pragma unroll
                for (int j = 0; j < 8; ++j) acc[j] += f[j];
            }
        }
        #pragma unroll
        for (int j = 0; j < 8; ++j) {
            acc[j] += __shfl_xor(acc[j], 16, 64);
            acc[j] += __shfl_xor(acc[j], 32, 64);
        }
        if (eq == 0) {
            u32 w[4];
            #pragma unroll
            for (int q = 0; q < 4; ++q)
                w[q] = (u32)f2bf(dv * acc[2 * q]) | ((u32)f2bf(dv * acc[2 * q + 1]) << 16);
            int chunk = l15 ^ (r & 7);
            *reinterpret_cast<uint4*>(&As[r * 128 + chunk * 8]) =
                make_uint4(w[0], w[1], w[2], w[3]);
        }
    }
    __syncthreads();

    // ---- phase 2: GEMM. wave w: row-tile rt=w&1, col-pair q=w>>2 (c0=2q,2q+1) ----
    const int rt = wave & 1, q = wave >> 1;   // q in 0..3
    const int rgrp = lane >> 4;

    bf16x8 a[4];
    #pragma unroll
    for (int k0 = 0; k0 < 4; ++k0) {
        int r = rt * 16 + l15;
        int chunk = (k0 * 4 + rgrp) ^ (r & 7);
        a[k0] = *reinterpret_cast<const bf16x8*>(&As[r * 128 + chunk * 8]);
    }

    f32x4 acc2[2];
    acc2[0] = f32x4{0.f, 0.f, 0.f, 0.f};
    acc2[1] = f32x4{0.f, 0.f, 0.f, 0.f};
    #pragma unroll
    for (int p = 0; p < 2; ++p) {
        const int c0 = 2 * q + p;
        #pragma unroll
        for (int k0 = 0; k0 < 4; ++k0) {
            bf16x8 b = *reinterpret_cast<const bf16x8*>(wf + ((c0 * 4 + k0) * 64 + lane) * 8);
            acc2[p] = __builtin_amdgcn_mfma_f32_16x16x32_bf16(a[k0], b, acc2[p], 0, 0, 0);
        }
    }

    // cols: l15*8 + 2q + {0,1}
    const int colb = l15 * 8 + 2 * q;
    float b0 = bias[colb], b1 = bias[colb + 1];
    float cp0 = 0.f, cp1 = 0.f, cq0 = 0.f, cq1 = 0.f;
    #pragma unroll
    for (int reg = 0; reg < 4; ++reg) {
        int row = base + rt * 16 + rgrp * 4 + reg;
        if (row < NN) {
            float v0 = acc2[0][reg] + b0;
            float v1 = acc2[1][reg] + b1;
            *reinterpret_cast<u32*>(agg + (size_t)row * HD + colb) =
                (u32)f2bf(v0) | ((u32)f2bf(v1) << 16);
            cp0 += v0; cp1 += v1; cq0 += v0 * v0; cq1 += v1 * v1;
        }
    }
    cp0 += __shfl_xor(cp0, 16, 64); cp0 += __shfl_xor(cp0, 32, 64);
    cp1 += __shfl_xor(cp1, 16, 64); cp1 += __shfl_xor(cp1, 32, 64);
    cq0 += __shfl_xor(cq0, 16, 64); cq0 += __shfl_xor(cq0, 32, 64);
    cq1 += __shfl_xor(cq1, 16, 64); cq1 += __shfl_xor(cq1, 32, 64);
    if (rgrp == 0) {                      // 2-way contention per col (rt=0,1)
        atomicAdd(&cs_l[colb], cp0); atomicAdd(&cs_l[colb + 1], cp1);
        atomicAdd(&cq_l[colb], cq0); atomicAdd(&cq_l[colb + 1], cq1);
    }
    __syncthreads();
    if (tid < 128) {
        colpart[(size_t)blockIdx.x * 256 + tid] = cs_l[tid];
        colpart[(size_t)blockIdx.x * 256 + 128 + tid] = cq_l[tid];
    }
}

// ---- stats reduce stage A: AGB partial rows -> 64 ----
__global__ __launch_bounds__(256) void reduceA_kernel(const float* __restrict__ colpart,
                                                      float* __restrict__ colpart2) {
    int slot = threadIdx.x;
    float s = 0.f;
    for (int b = blockIdx.x; b < AGB; b += 64) s += colpart[(size_t)b * 256 + slot];
    colpart2[(size_t)blockIdx.x * 256 + slot] = s;
}

// ---- stats finalize ----
__global__ __launch_bounds__(256) void stats_kernel(const float* __restrict__ colpart2,
                                                    const float* __restrict__ gamma,
                                                    const float* __restrict__ beta,
                                                    float* __restrict__ sc, float* __restrict__ sh) {
    __shared__ float sums[256];
    int slot = threadIdx.x;
    float s = 0.f;
    for (int b = 0; b < 64; ++b) s += colpart2[(size_t)b * 256 + slot];
    sums[slot] = s;
    __syncthreads();
    if (slot < 128) {
        float m = sums[slot] * (1.f / NN);
        float var = sums[128 + slot] * (1.f / NN) - m * m;
        float inv = rsqrtf(var + 1e-5f);
        float scl = gamma[slot] * inv;
        sc[slot] = scl;
        sh[slot] = beta[slot] - m * scl;
    }
}

// ---- normalize + ReLU + residual ----
__global__ void final_kernel(const u16* __restrict__ agg, const float* __restrict__ last_x,
                             const float* __restrict__ sc, const float* __restrict__ sh,
                             float* __restrict__ out) {
    int idx = blockIdx.x * blockDim.x + threadIdx.x;   // NN*HD/4 threads
    int c0 = (idx * 4) & 127;
    uint2 a = reinterpret_cast<const uint2*>(agg)[idx];
    float4 lx = reinterpret_cast<const float4*>(last_x)[idx];
    float f0 = __uint_as_float(a.x << 16), f1 = __uint_as_float(a.x & 0xFFFF0000u);
    float f2 = __uint_as_float(a.y << 16), f3 = __uint_as_float(a.y & 0xFFFF0000u);
    float4 o;
    o.x = fmaxf(fmaf(f0, sc[c0 + 0], sh[c0 + 0]), 0.f) + lx.x;
    o.y = fmaxf(fmaf(f1, sc[c0 + 1], sh[c0 + 1]), 0.f) + lx.y;
    o.z = fmaxf(fmaf(f2, sc[c0 + 2], sh[c0 + 2]), 0.f) + lx.z;
    o.w = fmaxf(fmaf(f3, sc[c0 + 3], sh[c0 + 3]), 0.f) + lx.w;
    reinterpret_cast<float4*>(out)[idx] = o;
}

extern "C" void kernel_launch(void* const* d_in, const int* in_sizes, int n_in,
                              void* d_out, int out_size, void* d_ws, size_t ws_size,
                              hipStream_t stream) {
    const float* x      = (const float*)d_in[0];
    const float* last_x = (const float*)d_in[1];
    const int*   edge   = (const int*)d_in[2];   // [2][NE]
    const float* W      = (const float*)d_in[3];
    const float* bias   = (const float*)d_in[4];
    const float* gamma  = (const float*)d_in[5];
    const float* beta   = (const float*)d_in[6];
    float* out = (float*)d_out;

    char* ws = (char*)d_ws;
    size_t p = 0;
    auto take = [&](size_t bytes) { size_t r = p; p += (bytes + 255) & ~255ULL; return r; };
    u32*   bcnt     = (u32*)(ws + take((size_t)NB * 4));
    u32*   bstart   = (u32*)(ws + take((size_t)NB * 4));
    u32*   ebuf     = (u32*)(ws + take((size_t)NB * GCAP * 4));
    u32*   rowptr   = (u32*)(ws + take((size_t)(NN + 1) * 4));
    u16*   srclist  = (u16*)(ws + take((size_t)NE * 2));
    float* dinv     = (float*)(ws + take((size_t)NN * 4));
    u16*   xs       = (u16*)(ws + take((size_t)NN * HD * 2));
    u16*   aggb     = (u16*)(ws + take((size_t)NN * HD * 2));
    u16*   wf       = (u16*)(ws + take((size_t)HD * HD * 2));
    float* colpart  = (float*)(ws + take((size_t)AGB * 256 * 4));
    float* colpart2 = (float*)(ws + take((size_t)64 * 256 * 4));
    float* sc       = (float*)(ws + take((size_t)HD * 4));
    float* sh       = (float*)(ws + take((size_t)HD * 4));

    const int* srcp = edge;
    const int* dstp = edge + NE;

    prep_kernel<<<64, 256, 0, stream>>>(W, wf, bcnt);
    part_kernel<<<PART_NBLK, 256, 0, stream>>>(srcp, dstp, bcnt, ebuf);
    bscan_kernel<<<1, 512, 0, stream>>>(bcnt, bstart);
    bucket_kernel<<<NB, 256, 0, stream>>>(ebuf, bcnt, bstart, rowptr, dinv, srclist);
    xscale_kernel<<<(NN * HD / 4) / 256, 256, 0, stream>>>(x, dinv, xs);
    aggemm_kernel<<<AGB, 512, 0, stream>>>(xs, rowptr, srclist, dinv, wf, bias, aggb, colpart);
    reduceA_kernel<<<64, 256, 0, stream>>>(colpart, colpart2);
    stats_kernel<<<1, 256, 0, stream>>>(colpart2, gamma, beta, sc, sh);
    final_kernel<<<(NN * HD / 4) / 256, 256, 0, stream>>>(aggb, last_x, sc, sh, out);
}